// Round 1
// baseline (530.531 us; speedup 1.0000x reference)
//
#include <hip/hip_runtime.h>

// ---------------------------------------------------------------------------
// MultiHeadAttention: x(2,2048,2048) f32; wq/wk/wv (2048,2048); wo (2048,2048)
// out(2,2048,2048) f32.  Pipeline: cast->bf16, GEMM Q/K/(V^T), RoPE(Q,K),
// causal flash attention, output GEMM (fp32 store).
// ---------------------------------------------------------------------------

typedef unsigned short u16;
typedef __attribute__((ext_vector_type(4))) float   f32x4;
typedef __attribute__((ext_vector_type(8))) short   short8;
typedef __attribute__((ext_vector_type(4))) u16     u16x4;
typedef __attribute__((ext_vector_type(2))) u16     u16x2;

#define NB   2
#define NH   16
#define SEQ  2048
#define DK   128
#define EMB  2048

__device__ __forceinline__ u16 f2bf(float f) {
    union { float f; unsigned int u; } v; v.f = f;
    unsigned int r = v.u + 0x7FFFu + ((v.u >> 16) & 1u);   // RTNE
    return (u16)(r >> 16);
}
__device__ __forceinline__ float bf2f(u16 h) {
    union { unsigned int u; float f; } v; v.u = ((unsigned int)h) << 16;
    return v.f;
}
__device__ __forceinline__ f32x4 mfma16(short8 a, short8 b, f32x4 c) {
    return __builtin_amdgcn_mfma_f32_16x16x32_bf16(a, b, c, 0, 0, 0);
}

#define GLDS(gsrc, ldst) __builtin_amdgcn_global_load_lds( \
    (const __attribute__((address_space(1))) void*)(gsrc), \
    (__attribute__((address_space(3))) void*)(ldst), 16, 0, 0)

// ---------------------------------------------------------------------------
// cast f32 -> bf16, 4 elems/thread
__global__ __launch_bounds__(256) void cast_f32_bf16(const float* __restrict__ in,
                                                     u16* __restrict__ out, int n4) {
    int i = blockIdx.x * 256 + threadIdx.x;
    if (i >= n4) return;
    f32x4 v = ((const f32x4*)in)[i];
    u16x4 o;
    o[0] = f2bf(v[0]); o[1] = f2bf(v[1]); o[2] = f2bf(v[2]); o[3] = f2bf(v[3]);
    ((u16x4*)out)[i] = o;
}

// cos/sin tables: (s, d2) d2 in [0,64)
__global__ __launch_bounds__(256) void rope_table(const float* __restrict__ freq,
                                                  float* __restrict__ ct,
                                                  float* __restrict__ st) {
    int i = blockIdx.x * 256 + threadIdx.x;          // 0..131071
    int s = i >> 6, d2 = i & 63;
    float pe = freq[s * DK + d2 * 2];
    ct[i] = cosf(pe);
    st[i] = sinf(pe);
}

// RoPE in place on Q,K (b,h,s,d) bf16. one thread per (bh, s, pair)
__global__ __launch_bounds__(256) void rope_apply(u16* __restrict__ Qb, u16* __restrict__ Kb,
                                                  const float* __restrict__ ct,
                                                  const float* __restrict__ st) {
    int i = blockIdx.x * 256 + threadIdx.x;          // 0 .. 32*2048*64-1
    int d2 = i & 63;
    int s  = (i >> 6) & (SEQ - 1);
    float c  = ct[(s << 6) + d2];
    float sn = st[(s << 6) + d2];
    size_t off = (size_t)i * 2;                      // == (bh*SEQ+s)*DK + 2*d2
    u16x2 q = *(const u16x2*)(Qb + off);
    float q0 = bf2f(q[0]), q1 = bf2f(q[1]);
    u16x2 qo; qo[0] = f2bf(q0 * c - q1 * sn); qo[1] = f2bf(q1 * c + q0 * sn);
    *(u16x2*)(Qb + off) = qo;
    u16x2 k = *(const u16x2*)(Kb + off);
    float k0 = bf2f(k[0]), k1 = bf2f(k[1]);
    u16x2 ko; ko[0] = f2bf(k0 * c - k1 * sn); ko[1] = f2bf(k1 * c + k0 * sn);
    *(u16x2*)(Kb + off) = ko;
}

// ---------------------------------------------------------------------------
// GEMM: C[m][n] = sum_k A[m][k] * B[n][k]   (both K-contiguous, bf16 in, f32 acc)
// 128x128 block tile, BK=32, 4 waves (2x2), 4x4 16x16 tiles per wave.
// MODE 0: store bf16 in (b,h,s,d): m=(b,s) n=(h,d)      [Q,K projection]
// MODE 1: store bf16 in (b,h,d,s): m=(h,d) n=(b,s)      [V^T projection]
// MODE 3: store f32 row-major m*N+n                     [output projection]
template <int MODE>
__global__ __launch_bounds__(256) void gemm_bt(const u16* __restrict__ A,
                                               const u16* __restrict__ B,
                                               void* __restrict__ Cout,
                                               int M, int N, int K) {
    __shared__ __align__(16) u16 As[128 * 32];
    __shared__ __align__(16) u16 Bs[128 * 32];
    const int tid  = threadIdx.x;
    const int lane = tid & 63;
    const int wid  = tid >> 6;
    const int wm   = wid >> 1, wn = wid & 1;
    const int m0   = blockIdx.x * 128, n0 = blockIdx.y * 128;
    const int lr   = lane & 15, lk = lane >> 4;
    const int srow = lane >> 2;          // staging: row within 16-row group
    const int sch  = (lane & 3) * 8;     // staging: element offset (16B chunk)

    f32x4 acc[4][4] = {};

    for (int k0 = 0; k0 < K; k0 += 32) {
        __syncthreads();
#pragma unroll
        for (int c = 0; c < 2; ++c) {
            int row = c * 64 + wid * 16 + srow;
            const u16* srcA = A + (size_t)(m0 + row) * K + k0 + sch;
            GLDS(srcA, &As[(c * 64 + wid * 16) * 32]);
            const u16* srcB = B + (size_t)(n0 + row) * K + k0 + sch;
            GLDS(srcB, &Bs[(c * 64 + wid * 16) * 32]);
        }
        __syncthreads();
        short8 af[4], bf[4];
#pragma unroll
        for (int i = 0; i < 4; ++i)
            af[i] = *(const short8*)&As[(wm * 64 + i * 16 + lr) * 32 + lk * 8];
#pragma unroll
        for (int j = 0; j < 4; ++j)
            bf[j] = *(const short8*)&Bs[(wn * 64 + j * 16 + lr) * 32 + lk * 8];
#pragma unroll
        for (int i = 0; i < 4; ++i)
#pragma unroll
            for (int j = 0; j < 4; ++j)
                acc[i][j] = mfma16(af[i], bf[j], acc[i][j]);
    }

#pragma unroll
    for (int i = 0; i < 4; ++i) {
#pragma unroll
        for (int j = 0; j < 4; ++j) {
#pragma unroll
            for (int r = 0; r < 4; ++r) {
                int m = m0 + wm * 64 + i * 16 + lk * 4 + r;
                int n = n0 + wn * 64 + j * 16 + lr;
                float v = acc[i][j][r];
                if (MODE == 0) {        // (b,h,s,d)
                    int b = m >> 11, s = m & (SEQ - 1), h = n >> 7, d = n & (DK - 1);
                    ((u16*)Cout)[(((size_t)(b * NH + h) * SEQ + s) * DK) + d] = f2bf(v);
                } else if (MODE == 1) { // (b,h,d,s)
                    int h = m >> 7, d = m & (DK - 1), b = n >> 11, s = n & (SEQ - 1);
                    ((u16*)Cout)[(((size_t)(b * NH + h) * DK + d) * SEQ) + s] = f2bf(v);
                } else {                // f32 row-major
                    ((float*)Cout)[(size_t)m * N + n] = v;
                }
            }
        }
    }
}

// ---------------------------------------------------------------------------
// Causal flash attention.
// grid: (qb=SEQ/64, bh=NB*NH). block 256 (4 waves, 16 q-rows each).
// Q,K: (b,h,s,d) bf16 (RoPE applied). VT: (b,h,d,s) bf16. O: (b,s,h*d) bf16.
__global__ __launch_bounds__(256) void attn_kernel(const u16* __restrict__ Q,
                                                   const u16* __restrict__ K,
                                                   const u16* __restrict__ VT,
                                                   u16* __restrict__ O) {
    const int qb = blockIdx.x;       // q block (64 rows)
    const int bh = blockIdx.y;       // 0..31
    const int tid = threadIdx.x, lane = tid & 63, w = tid >> 6;
    const int lr = lane & 15, lk = lane >> 4;
    const int q0 = qb * 64;

    __shared__ __align__(16) u16 Ksh[64 * 136];    // [key][d] pad 136
    __shared__ __align__(16) u16 Vsh[128 * 88];    // [d][key] pad 88
    __shared__ __align__(16) u16 Psh[4][16 * 80];  // per-wave P, pad 80

    const u16* Qg  = Q  + ((size_t)bh * SEQ + q0) * DK;
    const u16* Kg  = K  + (size_t)bh * SEQ * DK;
    const u16* VTg = VT + (size_t)bh * DK * SEQ;

    short8 qf[4];
#pragma unroll
    for (int ks = 0; ks < 4; ++ks)
        qf[ks] = *(const short8*)(Qg + (w * 16 + lr) * DK + ks * 32 + lk * 8);

    f32x4 oacc[8] = {};
    float mrow[4] = {-INFINITY, -INFINITY, -INFINITY, -INFINITY};
    float lsum[4] = {0.f, 0.f, 0.f, 0.f};

    for (int kt = 0; kt <= qb; ++kt) {
        __syncthreads();
        // stage K tile (64 keys x 128 d)
#pragma unroll
        for (int c = 0; c < 4; ++c) {
            int row = c * 16 + (tid >> 4);
            int ch  = (tid & 15) * 8;
            *(short8*)&Ksh[row * 136 + ch] =
                *(const short8*)(Kg + (size_t)(kt * 64 + row) * DK + ch);
        }
        // stage V^T tile (128 d x 64 keys)
#pragma unroll
        for (int c = 0; c < 4; ++c) {
            int d  = c * 32 + (tid >> 3);
            int ch = (tid & 7) * 8;
            *(short8*)&Vsh[d * 88 + ch] =
                *(const short8*)(VTg + (size_t)d * SEQ + kt * 64 + ch);
        }
        __syncthreads();

        // QK^T: 16 q-rows x 64 keys
        f32x4 sacc[4] = {};
#pragma unroll
        for (int ks = 0; ks < 4; ++ks)
#pragma unroll
            for (int nt = 0; nt < 4; ++nt) {
                short8 kf = *(const short8*)&Ksh[(nt * 16 + lr) * 136 + ks * 32 + lk * 8];
                sacc[nt] = mfma16(qf[ks], kf, sacc[nt]);
            }

        const float rs = 0.08838834764831845f;     // 1/sqrt(128)
        const bool diag = (kt == qb);
#pragma unroll
        for (int nt = 0; nt < 4; ++nt)
#pragma unroll
            for (int r = 0; r < 4; ++r) {
                float s = sacc[nt][r] * rs;
                if (diag) {
                    int keyg = kt * 64 + nt * 16 + lr;
                    int qg   = q0 + w * 16 + lk * 4 + r;
                    if (keyg > qg) s = -INFINITY;
                }
                sacc[nt][r] = s;
            }

        // online softmax (rows live across 16-lane groups; reg r = row lk*4+r)
        float p[4][4];
#pragma unroll
        for (int r = 0; r < 4; ++r) {
            float tm = fmaxf(fmaxf(sacc[0][r], sacc[1][r]), fmaxf(sacc[2][r], sacc[3][r]));
#pragma unroll
            for (int off = 1; off < 16; off <<= 1) tm = fmaxf(tm, __shfl_xor(tm, off));
            float mn = fmaxf(mrow[r], tm);
            float sc = __expf(mrow[r] - mn);
            mrow[r] = mn;
            lsum[r] *= sc;
            float rsumv = 0.f;
#pragma unroll
            for (int nt = 0; nt < 4; ++nt) {
                float pv = __expf(sacc[nt][r] - mn);
                p[nt][r] = pv;
                rsumv += pv;
            }
#pragma unroll
            for (int off = 1; off < 16; off <<= 1) rsumv += __shfl_xor(rsumv, off);
            lsum[r] += rsumv;
#pragma unroll
            for (int nd = 0; nd < 8; ++nd) oacc[nd][r] *= sc;
        }

        // P -> per-wave LDS (A-fragment relayout), bf16
#pragma unroll
        for (int nt = 0; nt < 4; ++nt)
#pragma unroll
            for (int r = 0; r < 4; ++r)
                Psh[w][(lk * 4 + r) * 80 + nt * 16 + lr] = f2bf(p[nt][r]);

        // PV: out(16 x 128) += P(16x64) @ V(64x128)
#pragma unroll
        for (int ks = 0; ks < 2; ++ks) {
            short8 pf = *(const short8*)&Psh[w][lr * 80 + ks * 32 + lk * 8];
#pragma unroll
            for (int nd = 0; nd < 8; ++nd) {
                short8 vf = *(const short8*)&Vsh[(nd * 16 + lr) * 88 + ks * 32 + lk * 8];
                oacc[nd] = mfma16(pf, vf, oacc[nd]);
            }
        }
    }

    // epilogue: O (b, s, h*128+d) bf16
    const int b = bh >> 4, h = bh & 15;
#pragma unroll
    for (int nd = 0; nd < 8; ++nd)
#pragma unroll
        for (int r = 0; r < 4; ++r) {
            int qrow = q0 + w * 16 + lk * 4 + r;
            float v = oacc[nd][r] / lsum[r];
            O[((size_t)b * SEQ + qrow) * EMB + h * DK + nd * 16 + lr] = f2bf(v);
        }
}

// ---------------------------------------------------------------------------
extern "C" void kernel_launch(void* const* d_in, const int* in_sizes, int n_in,
                              void* d_out, int out_size, void* d_ws, size_t ws_size,
                              hipStream_t stream) {
    const float* x    = (const float*)d_in[0];
    const float* wq   = (const float*)d_in[1];
    const float* wk   = (const float*)d_in[2];
    const float* wv   = (const float*)d_in[3];
    const float* wo   = (const float*)d_in[4];
    const float* freq = (const float*)d_in[5];

    char* ws = (char*)d_ws;
    u16*  xb  = (u16*)(ws);                          // 16,777,216 B
    u16*  wqb = (u16*)(ws + 16777216);               //  8,388,608
    u16*  wkb = (u16*)(ws + 25165824);
    u16*  wvb = (u16*)(ws + 33554432);
    u16*  wob = (u16*)(ws + 41943040);
    u16*  Qb  = (u16*)(ws + 50331648);               // 16,777,216
    u16*  Kb  = (u16*)(ws + 67108864);
    u16*  VTb = (u16*)(ws + 83886080);
    float* ct = (float*)(ws + 100663296);            //    524,288
    float* st = (float*)(ws + 101187584);
    u16*  attn = xb;                                 // alias: x dead after projections

    // casts
    cast_f32_bf16<<<8192, 256, 0, stream>>>(x,  xb,  2097152);
    cast_f32_bf16<<<4096, 256, 0, stream>>>(wq, wqb, 1048576);
    cast_f32_bf16<<<4096, 256, 0, stream>>>(wk, wkb, 1048576);
    cast_f32_bf16<<<4096, 256, 0, stream>>>(wv, wvb, 1048576);
    cast_f32_bf16<<<4096, 256, 0, stream>>>(wo, wob, 1048576);
    rope_table<<<512, 256, 0, stream>>>(freq, ct, st);

    // projections
    gemm_bt<0><<<dim3(32, 16), 256, 0, stream>>>(xb,  wqb, Qb,  4096, 2048, 2048);
    gemm_bt<0><<<dim3(32, 16), 256, 0, stream>>>(xb,  wkb, Kb,  4096, 2048, 2048);
    gemm_bt<1><<<dim3(16, 32), 256, 0, stream>>>(wvb, xb,  VTb, 2048, 4096, 2048);

    // RoPE on Q,K
    rope_apply<<<16384, 256, 0, stream>>>(Qb, Kb, ct, st);

    // attention
    attn_kernel<<<dim3(32, 32), 256, 0, stream>>>(Qb, Kb, VTb, attn);

    // output projection (f32 store)
    gemm_bt<3><<<dim3(32, 16), 256, 0, stream>>>(attn, wob, d_out, 4096, 2048, 2048);
}